// Round 1
// baseline (73.626 us; speedup 1.0000x reference)
//
#include <hip/hip_runtime.h>

namespace {
constexpr int BSZ = 5;
constexpr int Bn = 64, Cn = 128, Hn = 56, Wn = 56;
constexpr int HU = Hn - BSZ + 1;                  // 52
constexpr int WU = Wn - BSZ + 1;                  // 52
constexpr long long NX = (long long)Bn * Cn * Hn * Wn;   // 25690112
constexpr long long NU = (long long)Bn * Cn * HU * WU;   // 22151168
constexpr int PLANE_U = HU * WU;                  // 2704
constexpr int PLANE_X = Hn * Wn;                  // 3136
constexpr int MAXH = 8192;

struct Ctl {
  unsigned int nhits;
  unsigned int pad0;
  float gamma;
  float scale;
  unsigned int hits[MAXH];
};
}  // namespace

// ---------- kernel 1: init counter + compute gamma from num_batches_tracked ----------
__global__ void k_init(const int* __restrict__ nbt, Ctl* ctl) {
  double kr = 1.0 - 0.5 / 20000.0 * (double)nbt[0];
  if (kr < 0.5) kr = 0.5;  // max(1 - DR/20000*n, 1 - DR)
  double g = (1.0 - kr) / (double)(BSZ * BSZ) * (double)(Wn * Wn) /
             (double)((Wn - BSZ + 1) * (Wn - BSZ + 1));
  ctl->gamma = (float)g;
  ctl->nhits = 0u;
}

// ---------- kernel 2: scan u, compact hits (very sparse: ~25 expected) ----------
__global__ void k_scan(const float4* __restrict__ u4, long long n4, Ctl* ctl) {
  const float g = ctl->gamma;
  const long long stride = (long long)gridDim.x * blockDim.x;
  for (long long i = (long long)blockIdx.x * blockDim.x + threadIdx.x; i < n4; i += stride) {
    float4 v = u4[i];
    if (v.x < g || v.y < g || v.z < g || v.w < g) {  // almost never taken
      unsigned int base = (unsigned int)(4 * i);
      if (v.x < g) { unsigned int p = atomicAdd(&ctl->nhits, 1u); if (p < MAXH) ctl->hits[p] = base + 0u; }
      if (v.y < g) { unsigned int p = atomicAdd(&ctl->nhits, 1u); if (p < MAXH) ctl->hits[p] = base + 1u; }
      if (v.z < g) { unsigned int p = atomicAdd(&ctl->nhits, 1u); if (p < MAXH) ctl->hits[p] = base + 2u; }
      if (v.w < g) { unsigned int p = atomicAdd(&ctl->nhits, 1u); if (p < MAXH) ctl->hits[p] = base + 3u; }
    }
  }
}

// ---------- kernel 3: exact union size of 5x5 blocks, compute scale ----------
__global__ void k_count(Ctl* ctl) {
  __shared__ unsigned int s_total;
  if (threadIdx.x == 0) s_total = 0u;
  __syncthreads();
  const int n = (int)min(ctl->nhits, (unsigned int)MAXH);
  unsigned int local = 0;
  for (int t = threadIdx.x; t < n * 25; t += blockDim.x) {
    const int hi = t / 25;
    const int cell = t - hi * 25;
    const unsigned int e = ctl->hits[hi];
    const int plane = (int)(e / PLANE_U);
    const int rem = (int)(e - (unsigned int)plane * PLANE_U);
    const int i = rem / WU;
    const int j = rem - i * WU;
    const int hh = i + cell / 5;
    const int ww = j + cell % 5;
    // count this dilated cell only if no earlier hit in the same plane covers it
    bool covered = false;
    for (int p = 0; p < hi; ++p) {
      const unsigned int e2 = ctl->hits[p];
      const int pl2 = (int)(e2 / PLANE_U);
      if (pl2 != plane) continue;
      const int rem2 = (int)(e2 - (unsigned int)pl2 * PLANE_U);
      const int i2 = rem2 / WU;
      const int j2 = rem2 - i2 * WU;
      if (hh >= i2 && hh <= i2 + 4 && ww >= j2 && ww <= j2 + 4) { covered = true; break; }
    }
    if (!covered) local++;
  }
  if (local) atomicAdd(&s_total, local);
  __syncthreads();
  if (threadIdx.x == 0) {
    double count_ones = (double)NX - (double)s_total;
    ctl->scale = (float)((double)NX / count_ones);
  }
}

// ---------- kernel 4: out = x * scale (streaming) ----------
__global__ void k_mul(const float4* __restrict__ x4, float4* __restrict__ o4,
                      long long n4, const Ctl* __restrict__ ctl) {
  const float s = ctl->scale;
  const long long stride = (long long)gridDim.x * blockDim.x;
  for (long long i = (long long)blockIdx.x * blockDim.x + threadIdx.x; i < n4; i += stride) {
    float4 v = x4[i];
    v.x *= s; v.y *= s; v.z *= s; v.w *= s;
    o4[i] = v;
  }
}

// ---------- kernel 5: zero the dilated 5x5 blocks ----------
__global__ void k_zero(float* __restrict__ out, const Ctl* __restrict__ ctl) {
  const int n = (int)min(ctl->nhits, (unsigned int)MAXH);
  const int total = n * 25;
  const int stride = gridDim.x * blockDim.x;
  for (int t = blockIdx.x * blockDim.x + threadIdx.x; t < total; t += stride) {
    const int hi = t / 25;
    const int cell = t - hi * 25;
    const unsigned int e = ctl->hits[hi];
    const int plane = (int)(e / PLANE_U);
    const int rem = (int)(e - (unsigned int)plane * PLANE_U);
    const int i = rem / WU;
    const int j = rem - i * WU;
    const int hh = i + cell / 5;
    const int ww = j + cell % 5;
    out[(long long)plane * PLANE_X + (long long)hh * Wn + ww] = 0.0f;
  }
}

extern "C" void kernel_launch(void* const* d_in, const int* in_sizes, int n_in,
                              void* d_out, int out_size, void* d_ws, size_t ws_size,
                              hipStream_t stream) {
  const float* x = (const float*)d_in[0];
  const float* u = (const float*)d_in[1];
  const int* nbt = (const int*)d_in[2];
  float* out = (float*)d_out;
  Ctl* ctl = (Ctl*)d_ws;

  const long long nu4 = NU / 4;  // 5537792
  const long long nx4 = NX / 4;  // 6422528

  k_init<<<1, 1, 0, stream>>>(nbt, ctl);
  {
    int blocks = (int)min((long long)2048, (nu4 + 255) / 256);
    k_scan<<<blocks, 256, 0, stream>>>((const float4*)u, nu4, ctl);
  }
  k_count<<<1, 256, 0, stream>>>(ctl);
  {
    int blocks = (int)min((long long)2048, (nx4 + 255) / 256);
    k_mul<<<blocks, 256, 0, stream>>>((const float4*)x, (float4*)out, nx4, ctl);
  }
  k_zero<<<32, 256, 0, stream>>>(out, ctl);
}

// Round 2
// 69.734 us; speedup vs baseline: 1.0558x; 1.0558x over previous
//
#include <hip/hip_runtime.h>

namespace {
constexpr int BSZ = 5;
constexpr int Bn = 64, Cn = 128, Hn = 56, Wn = 56;
constexpr int HU = Hn - BSZ + 1;                  // 52
constexpr int WU = Wn - BSZ + 1;                  // 52
constexpr long long NX = (long long)Bn * Cn * Hn * Wn;   // 25690112
constexpr long long NU = (long long)Bn * Cn * HU * WU;   // 22151168
constexpr int PLANE_U = HU * WU;                  // 2704
constexpr int PLANE_X = Hn * Wn;                  // 3136
constexpr int MAXH = 8192;

constexpr int NU4 = (int)(NU / 4);                // 5537792 = 256 * 21632
constexpr int NX4 = (int)(NX / 4);                // 6422528 = 256 * 25088
constexpr int SCAN_BLOCKS = NU4 / 256;            // 21632, exact
constexpr int MUL_BLOCKS = NX4 / 256;             // 25088, exact

struct Ctl {
  unsigned int nhits;   // offset 0 — reset via hipMemsetAsync each call
  unsigned int pad0;
  float scale;
  unsigned int hits[MAXH];
};
}  // namespace

// ---------- kernel 1: scan u, compact hits (very sparse: ~25 expected) ----------
// gamma computed inline with the EXACT double-op sequence of the reference
// (verified bit-identical in round 1: absmax == 0).
__global__ __launch_bounds__(256) void k_scan(const float4* __restrict__ u4,
                                              const int* __restrict__ nbt,
                                              Ctl* ctl) {
  double kr = 1.0 - 0.5 / 20000.0 * (double)nbt[0];
  if (kr < 0.5) kr = 0.5;
  double gd = (1.0 - kr) / (double)(BSZ * BSZ) * (double)(Wn * Wn) /
              (double)((Wn - BSZ + 1) * (Wn - BSZ + 1));
  const float g = (float)gd;

  const int i = blockIdx.x * 256 + threadIdx.x;  // exact grid, no guard
  float4 v = u4[i];
  if (v.x < g || v.y < g || v.z < g || v.w < g) {  // almost never taken
    unsigned int base = (unsigned int)(4 * i);
    if (v.x < g) { unsigned int p = atomicAdd(&ctl->nhits, 1u); if (p < MAXH) ctl->hits[p] = base + 0u; }
    if (v.y < g) { unsigned int p = atomicAdd(&ctl->nhits, 1u); if (p < MAXH) ctl->hits[p] = base + 1u; }
    if (v.z < g) { unsigned int p = atomicAdd(&ctl->nhits, 1u); if (p < MAXH) ctl->hits[p] = base + 2u; }
    if (v.w < g) { unsigned int p = atomicAdd(&ctl->nhits, 1u); if (p < MAXH) ctl->hits[p] = base + 3u; }
  }
}

// ---------- kernel 2: exact union size of 5x5 blocks, compute scale ----------
__global__ void k_count(Ctl* ctl) {
  __shared__ unsigned int s_total;
  if (threadIdx.x == 0) s_total = 0u;
  __syncthreads();
  const int n = (int)min(ctl->nhits, (unsigned int)MAXH);
  unsigned int local = 0;
  for (int t = threadIdx.x; t < n * 25; t += blockDim.x) {
    const int hi = t / 25;
    const int cell = t - hi * 25;
    const unsigned int e = ctl->hits[hi];
    const int plane = (int)(e / PLANE_U);
    const int rem = (int)(e - (unsigned int)plane * PLANE_U);
    const int i = rem / WU;
    const int j = rem - i * WU;
    const int hh = i + cell / 5;
    const int ww = j + cell % 5;
    // count this dilated cell only if no earlier hit in the same plane covers it
    bool covered = false;
    for (int p = 0; p < hi; ++p) {
      const unsigned int e2 = ctl->hits[p];
      const int pl2 = (int)(e2 / PLANE_U);
      if (pl2 != plane) continue;
      const int rem2 = (int)(e2 - (unsigned int)pl2 * PLANE_U);
      const int i2 = rem2 / WU;
      const int j2 = rem2 - i2 * WU;
      if (hh >= i2 && hh <= i2 + 4 && ww >= j2 && ww <= j2 + 4) { covered = true; break; }
    }
    if (!covered) local++;
  }
  if (local) atomicAdd(&s_total, local);
  __syncthreads();
  if (threadIdx.x == 0) {
    double count_ones = (double)NX - (double)s_total;
    ctl->scale = (float)((double)NX / count_ones);
  }
}

// ---------- kernel 3: out = x * scale — copy-style, one float4 per thread ----------
__global__ __launch_bounds__(256) void k_mul(const float4* __restrict__ x4,
                                             float4* __restrict__ o4,
                                             const Ctl* __restrict__ ctl) {
  const float s = ctl->scale;
  const int i = blockIdx.x * 256 + threadIdx.x;  // exact grid, no guard
  float4 v = x4[i];
  v.x *= s; v.y *= s; v.z *= s; v.w *= s;
  o4[i] = v;
}

// ---------- kernel 4: zero the dilated 5x5 blocks (~25*25 stores) ----------
__global__ void k_zero(float* __restrict__ out, const Ctl* __restrict__ ctl) {
  const int n = (int)min(ctl->nhits, (unsigned int)MAXH);
  const int total = n * 25;
  const int stride = gridDim.x * blockDim.x;
  for (int t = blockIdx.x * blockDim.x + threadIdx.x; t < total; t += stride) {
    const int hi = t / 25;
    const int cell = t - hi * 25;
    const unsigned int e = ctl->hits[hi];
    const int plane = (int)(e / PLANE_U);
    const int rem = (int)(e - (unsigned int)plane * PLANE_U);
    const int i = rem / WU;
    const int j = rem - i * WU;
    const int hh = i + cell / 5;
    const int ww = j + cell % 5;
    out[(long long)plane * PLANE_X + (long long)hh * Wn + ww] = 0.0f;
  }
}

extern "C" void kernel_launch(void* const* d_in, const int* in_sizes, int n_in,
                              void* d_out, int out_size, void* d_ws, size_t ws_size,
                              hipStream_t stream) {
  const float* x = (const float*)d_in[0];
  const float* u = (const float*)d_in[1];
  const int* nbt = (const int*)d_in[2];
  float* out = (float*)d_out;
  Ctl* ctl = (Ctl*)d_ws;

  // reset hit counter (d_ws is NOT re-poisoned between replays)
  hipMemsetAsync(ctl, 0, 8, stream);
  k_scan<<<SCAN_BLOCKS, 256, 0, stream>>>((const float4*)u, nbt, ctl);
  k_count<<<1, 256, 0, stream>>>(ctl);
  k_mul<<<MUL_BLOCKS, 256, 0, stream>>>((const float4*)x, (float4*)out, ctl);
  k_zero<<<16, 256, 0, stream>>>(out, ctl);
}